// Round 4
// baseline (4009.826 us; speedup 1.0000x reference)
//
#include <hip/hip_runtime.h>

#define N_USERS 100000
#define N_ITEMS 50000
#define N_NODES 150000
#define NNZ     3200000
#define DIM     64
#define BATCH   8192

#define BKT_SHIFT 9
#define BKTSZ     (1 << BKT_SHIFT)                        // 512 nodes / bucket
#define NBKT      ((N_NODES + BKTSZ - 1) >> BKT_SHIFT)    // 293
#define ITEM_BKT0 (N_USERS >> BKT_SHIFT)                  // 195 (partial bucket)
#define SRC_MASK  0x3FFFF                                 // 18 bits

#define SBIN_SHIFT 8
#define NSBIN      ((N_NODES + (1 << SBIN_SHIFT) - 1) >> SBIN_SHIFT)   // 586

#define P1_THREADS 512
#define P1_PER_T   16
#define P1_CHUNK   (P1_THREADS * P1_PER_T)                // 8192 edges / block
#define P1_BLOCKS  ((NNZ + P1_CHUNK - 1) / P1_CHUNK)      // 391

#define ACC_STRIDE 65                                     // 64 + 1 pad (bank spread)

// ---------------- workspace layout (bytes) ----------------
// 0           bufA     38,400,000   (tmp int2 25.6MB aliases bufA; tmp is dead
// 38400000    bufB     38,400,000    after k_sort, bufA first written layer 2)
// 76800000    itemsum  12,800,000
// 89600000    edges    25,600,000   (NNZ * int2 : packed, val)
// 115200000   ghist         4,096
// 115204096   bbase         4,096   (NBKT+1)
// 115208192   bhead         4,096
// total ≈ 115.2 MB

__global__ __launch_bounds__(512) void k_zero_i32(int* __restrict__ p, int n) {
    for (int i = blockIdx.x * blockDim.x + threadIdx.x; i < n; i += gridDim.x * blockDim.x)
        p[i] = 0;
}

__global__ __launch_bounds__(256) void k_hist(const int* __restrict__ dst, int* __restrict__ gh) {
    __shared__ int h[NBKT];
    for (int i = threadIdx.x; i < NBKT; i += 256) h[i] = 0;
    __syncthreads();
    for (int i = blockIdx.x * 256 + threadIdx.x; i < NNZ; i += gridDim.x * 256)
        atomicAdd(&h[dst[i] >> BKT_SHIFT], 1);
    __syncthreads();
    for (int i = threadIdx.x; i < NBKT; i += 256) atomicAdd(&gh[i], h[i]);
}

__global__ __launch_bounds__(512) void k_scan(const int* __restrict__ gh,
                                              int* __restrict__ bbase,
                                              int* __restrict__ bhead) {
    __shared__ int sh[512];
    const int t = threadIdx.x;
    int v = (t < NBKT) ? gh[t] : 0;
    sh[t] = v; __syncthreads();
    for (int o = 1; o < 512; o <<= 1) {
        int a = (t >= o) ? sh[t - o] : 0;
        __syncthreads();
        sh[t] += a;
        __syncthreads();
    }
    int ex = sh[t] - v;
    if (t < NBKT) { bbase[t] = ex; bhead[t] = ex; }
    if (t == 0)   bbase[NBKT] = NNZ;
}

// Pass 1: bin edges by dst-bucket; block-local LDS ranking -> contiguous runs.
__global__ __launch_bounds__(P1_THREADS) void k_pass1(const int* __restrict__ src,
                                                      const int* __restrict__ dst,
                                                      const float* __restrict__ val,
                                                      int* __restrict__ bhead,
                                                      int2* __restrict__ tmp) {
    __shared__ int cnt[NBKT];
    __shared__ int base[NBKT];
    const int t = threadIdx.x;
    const int c0 = blockIdx.x * P1_CHUNK;
    for (int i = t; i < NBKT; i += P1_THREADS) cnt[i] = 0;
    __syncthreads();
    int pk[P1_PER_T], rk[P1_PER_T], bk[P1_PER_T]; float vv[P1_PER_T];
    #pragma unroll
    for (int k = 0; k < P1_PER_T; ++k) {
        const int i = c0 + k * P1_THREADS + t;
        if (i < NNZ) {
            const int d = dst[i];
            bk[k] = d >> BKT_SHIFT;
            pk[k] = src[i] | ((d & (BKTSZ - 1)) << 18);
            vv[k] = val[i];
            rk[k] = atomicAdd(&cnt[bk[k]], 1);
        } else bk[k] = -1;
    }
    __syncthreads();
    for (int i = t; i < NBKT; i += P1_THREADS) base[i] = atomicAdd(&bhead[i], cnt[i]);
    __syncthreads();
    #pragma unroll
    for (int k = 0; k < P1_PER_T; ++k)
        if (bk[k] >= 0)
            tmp[base[bk[k]] + rk[k]] = make_int2(pk[k], __float_as_int(vv[k]));
}

// Per-bucket counting sort by coarse src bin (src>>8) -> src-ordered edges.
__global__ __launch_bounds__(1024) void k_sort(const int* __restrict__ bbase,
                                               const int2* __restrict__ tmp,
                                               int2* __restrict__ edges) {
    __shared__ int cnt[NSBIN];
    __shared__ int sh[1024];
    const int b = blockIdx.x, t = threadIdx.x;
    const int start = bbase[b], end = bbase[b + 1];
    for (int i = t; i < NSBIN; i += 1024) cnt[i] = 0;
    __syncthreads();
    for (int i = start + t; i < end; i += 1024)
        atomicAdd(&cnt[(tmp[i].x & SRC_MASK) >> SBIN_SHIFT], 1);
    __syncthreads();
    int v = (t < NSBIN) ? cnt[t] : 0;
    sh[t] = v; __syncthreads();
    for (int o = 1; o < 1024; o <<= 1) {
        int a = (t >= o) ? sh[t - o] : 0;
        __syncthreads();
        sh[t] += a;
        __syncthreads();
    }
    if (t < NSBIN) cnt[t] = start + sh[t] - v;   // exclusive running head
    __syncthreads();
    for (int i = start + t; i < end; i += 1024) {
        int2 e = tmp[i];
        int pos = atomicAdd(&cnt[(e.x & SRC_MASK) >> SBIN_SHIFT], 1);
        edges[pos] = e;
    }
}

// Push SpMM: one block per dst-bucket, 512 rows of f32 acc in LDS.
// Streams src-sorted edges -> device-wide src window is L2-resident.
// MODE 0: x = user_emb, skip item srcs; y <- acc; itemsum <- item_emb0 + acc.
// MODE 1: full gather; y <- acc; itemsum += acc.
// MODE 2: item buckets only; no y; itemsum += acc.
template<int MODE>
__global__ __launch_bounds__(1024) void k_push(const int* __restrict__ bbase,
                                               const int2* __restrict__ edges,
                                               const float4* __restrict__ x4,
                                               const float4* __restrict__ ie4,
                                               float4* __restrict__ y4,
                                               float4* __restrict__ isum4) {
    __shared__ float acc[BKTSZ * ACC_STRIDE];   // 133 KB
    const int t = threadIdx.x;
    const int w = t >> 6;           // wave 0..15
    const int lane = t & 63;
    const int g = lane >> 4;        // edge slot in wave
    const int q = lane & 15;        // float4 column
    int b = blockIdx.x;
    if (MODE == 2) b += ITEM_BKT0;
    const int nodebase = b << BKT_SHIFT;
    const int start = bbase[b], end = bbase[b + 1];

    for (int i = t; i < BKTSZ * ACC_STRIDE; i += 1024) acc[i] = 0.0f;
    __syncthreads();

    for (int base = start + (w << 2); base < end; base += 64) {
        const int ei = base + g;
        if (ei < end) {
            const int2 e = edges[ei];
            const int src  = e.x & SRC_MASK;
            const int dloc = (e.x >> 18) & (BKTSZ - 1);
            const float v  = __int_as_float(e.y);
            bool active = true;
            if (MODE == 0) active = (src < N_USERS);
            if (MODE == 2) active = (nodebase + dloc >= N_USERS);
            if (active) {
                const float4 xr = x4[(size_t)src * 16 + q];
                float* row = &acc[dloc * ACC_STRIDE + (q << 2)];
                atomicAdd(row + 0, v * xr.x);
                atomicAdd(row + 1, v * xr.y);
                atomicAdd(row + 2, v * xr.z);
                atomicAdd(row + 3, v * xr.w);
            }
        }
    }
    __syncthreads();

    for (int i4 = t; i4 < BKTSZ * 16; i4 += 1024) {
        const int row = i4 >> 4, qq = i4 & 15;
        const int node = nodebase + row;
        if (node >= N_NODES) continue;
        const float* rp_ = &acc[row * ACC_STRIDE + (qq << 2)];
        float4 a = make_float4(rp_[0], rp_[1], rp_[2], rp_[3]);
        if (MODE != 2) y4[(size_t)node * 16 + qq] = a;
        if (node >= N_USERS) {
            const size_t io = (size_t)(node - N_USERS) * 16 + qq;
            if (MODE == 0) {
                const float4 iv = ie4[io];
                isum4[io] = make_float4(iv.x + a.x, iv.y + a.y, iv.z + a.z, iv.w + a.w);
            } else {
                float4 tv = isum4[io];
                tv.x += a.x; tv.y += a.y; tv.z += a.z; tv.w += a.w;
                isum4[io] = tv;
            }
        }
    }
}

// one wave per batch element: gamma = u.b + (u^T W) . (itemsum*0.25)
__global__ __launch_bounds__(256) void k_final(const float* __restrict__ ue,
                                               const float* __restrict__ isum,
                                               const float* __restrict__ W,
                                               const float* __restrict__ bvec,
                                               const int* __restrict__ users,
                                               const int* __restrict__ items,
                                               float* __restrict__ out) {
    __shared__ float Ws[DIM * DIM];
    const int t = threadIdx.x;
    for (int i = t; i < DIM * DIM; i += 256) Ws[i] = W[i];
    __syncthreads();

    const int gw = blockIdx.x * 4 + (t >> 6);
    const int lane = t & 63;
    if (gw >= BATCH) return;
    const int u  = users[gw];
    const int it = items[gw];

    float u_l = ue[(size_t)u * DIM + lane];
    float m_l = isum[(size_t)it * DIM + lane] * 0.25f;
    float b_l = bvec[lane];

    float v = 0.0f;
    for (int j = 0; j < DIM; ++j) {
        float uj = __shfl(u_l, j);
        v = fmaf(uj, Ws[j * DIM + lane], v);
    }
    float p = fmaf(v, m_l, u_l * b_l);
    for (int o = 32; o > 0; o >>= 1) p += __shfl_xor(p, o);
    if (lane == 0) out[gw] = p;
}

extern "C" void kernel_launch(void* const* d_in, const int* in_sizes, int n_in,
                              void* d_out, int out_size, void* d_ws, size_t ws_size,
                              hipStream_t stream) {
    const float* user_emb  = (const float*)d_in[0];
    const float* item_emb0 = (const float*)d_in[1];
    const float* edge_val  = (const float*)d_in[2];
    const float* W         = (const float*)d_in[3];
    const float* bvec      = (const float*)d_in[4];
    const int*   edge_src  = (const int*)d_in[5];
    const int*   edge_dst  = (const int*)d_in[6];
    const int*   users     = (const int*)d_in[7];
    const int*   items     = (const int*)d_in[8];
    float* out = (float*)d_out;

    char* ws = (char*)d_ws;
    float* bufA    = (float*)(ws + 0);
    float* bufB    = (float*)(ws + 38400000);
    float* itemsum = (float*)(ws + 76800000);
    int2*  tmp     = (int2*) (ws + 0);            // aliases bufA (dead after k_sort)
    int2*  edges   = (int2*) (ws + 89600000);
    int*   ghist   = (int*)  (ws + 115200000);
    int*   bbase   = (int*)  (ws + 115204096);
    int*   bhead   = (int*)  (ws + 115208192);

    // build: dst-bucket binning + per-bucket src sort
    k_zero_i32<<<1, 512, 0, stream>>>(ghist, NBKT);
    k_hist<<<512, 256, 0, stream>>>(edge_dst, ghist);
    k_scan<<<1, 512, 0, stream>>>(ghist, bbase, bhead);
    k_pass1<<<P1_BLOCKS, P1_THREADS, 0, stream>>>(edge_src, edge_dst, edge_val, bhead, tmp);
    k_sort<<<NBKT, 1024, 0, stream>>>(bbase, tmp, edges);

    // 3 push-SpMM layers
    k_push<0><<<NBKT, 1024, 0, stream>>>(bbase, edges, (const float4*)user_emb,
                                         (const float4*)item_emb0,
                                         (float4*)bufB, (float4*)itemsum);
    k_push<1><<<NBKT, 1024, 0, stream>>>(bbase, edges, (const float4*)bufB,
                                         nullptr, (float4*)bufA, (float4*)itemsum);
    k_push<2><<<NBKT - ITEM_BKT0, 1024, 0, stream>>>(bbase, edges, (const float4*)bufA,
                                                     nullptr, nullptr, (float4*)itemsum);

    // final dot products
    k_final<<<(BATCH + 3) / 4, 256, 0, stream>>>(user_emb, itemsum, W, bvec,
                                                 users, items, out);
}

// Round 5
// 275.466 us; speedup vs baseline: 14.5565x; 14.5565x over previous
//
#include <hip/hip_runtime.h>
#include <hip/hip_fp16.h>

#define N_USERS 100000
#define N_ITEMS 50000
#define N_NODES 150000
#define NNZ     3200000
#define DIM     64
#define BATCH   8192

#define BKT_SHIFT 10
#define BKTSZ     (1 << BKT_SHIFT)                        // 1024 nodes / bucket
#define NBKT      ((N_NODES + BKTSZ - 1) >> BKT_SHIFT)    // 147
#define SRC_MASK  0x3FFFF                                 // 18 bits (N_NODES < 2^18)

#define P1_THREADS 512
#define P1_PER_T   16
#define P1_CHUNK   (P1_THREADS * P1_PER_T)                // 8192 edges / block
#define P1_BLOCKS  ((NNZ + P1_CHUNK - 1) / P1_CHUNK)      // 391

// ---------------- workspace layout (bytes) ----------------
// 0           bufA16   19,200,000   (150000*64*2, fp16)
// 19200000    bufB16   19,200,000
// 38400000    xu16     12,800,000   (100000*64*2, fp16 user_emb)
// 51200000    itemsum  12,800,000   (f32)
// 64000000    edges    25,600,000   (NNZ * int2 : src, f32 val)
// 89600000    tmp      25,600,000   (NNZ * int2, binning scratch)
// 115200000   rp          600,064   (N_NODES+1)
// 115800064   ghist         1,024
// 115801088   bbase         1,024
// 115802112   bhead         1,024
// total ≈ 115.8 MB

__global__ __launch_bounds__(256) void k_zero_i32(int* __restrict__ p, int n) {
    for (int i = blockIdx.x * blockDim.x + threadIdx.x; i < n; i += gridDim.x * blockDim.x)
        p[i] = 0;
}

// f32 user_emb -> fp16 gather table
__global__ __launch_bounds__(256) void k_conv(const float4* __restrict__ ue,
                                              uint2* __restrict__ xu) {
    const int n = N_USERS * 16;
    for (int i = blockIdx.x * blockDim.x + threadIdx.x; i < n; i += gridDim.x * blockDim.x) {
        float4 v = ue[i];
        union { unsigned u; __half2 h; } a0, a1;
        a0.h = __floats2half2_rn(v.x, v.y);
        a1.h = __floats2half2_rn(v.z, v.w);
        xu[i] = make_uint2(a0.u, a1.u);
    }
}

// coarse 147-bucket histogram, LDS-privatized
__global__ __launch_bounds__(256) void k_hist147(const int* __restrict__ dst, int* __restrict__ gh) {
    __shared__ int h[NBKT];
    for (int i = threadIdx.x; i < NBKT; i += 256) h[i] = 0;
    __syncthreads();
    for (int i = blockIdx.x * 256 + threadIdx.x; i < NNZ; i += gridDim.x * 256)
        atomicAdd(&h[dst[i] >> BKT_SHIFT], 1);
    __syncthreads();
    for (int i = threadIdx.x; i < NBKT; i += 256) atomicAdd(&gh[i], h[i]);
}

// exclusive scan of 147 bucket counts
__global__ __launch_bounds__(256) void k_scan147(const int* __restrict__ gh,
                                                 int* __restrict__ bbase,
                                                 int* __restrict__ bhead,
                                                 int* __restrict__ rp) {
    __shared__ int sh[256];
    const int t = threadIdx.x;
    int v = (t < NBKT) ? gh[t] : 0;
    sh[t] = v; __syncthreads();
    for (int o = 1; o < 256; o <<= 1) {
        int a = (t >= o) ? sh[t - o] : 0;
        __syncthreads();
        sh[t] += a;
        __syncthreads();
    }
    int ex = sh[t] - v;
    if (t < NBKT) { bbase[t] = ex; bhead[t] = ex; }
    if (t == 0)   { bbase[NBKT] = NNZ; rp[N_NODES] = NNZ; }
}

// Pass 1: bin edges into 147 buckets; block-local LDS ranking -> contiguous runs.
__global__ __launch_bounds__(P1_THREADS) void k_pass1(const int* __restrict__ src,
                                                      const int* __restrict__ dst,
                                                      const float* __restrict__ val,
                                                      int* __restrict__ bhead,
                                                      int2* __restrict__ tmp) {
    __shared__ int cnt[NBKT];
    __shared__ int base[NBKT];
    const int t = threadIdx.x;
    const int c0 = blockIdx.x * P1_CHUNK;
    for (int i = t; i < NBKT; i += P1_THREADS) cnt[i] = 0;
    __syncthreads();
    int pk[P1_PER_T], rk[P1_PER_T], bk[P1_PER_T]; float vv[P1_PER_T];
    #pragma unroll
    for (int k = 0; k < P1_PER_T; ++k) {
        const int i = c0 + k * P1_THREADS + t;
        if (i < NNZ) {
            const int d = dst[i];
            bk[k] = d >> BKT_SHIFT;
            pk[k] = src[i] | ((d & (BKTSZ - 1)) << 18);
            vv[k] = val[i];
            rk[k] = atomicAdd(&cnt[bk[k]], 1);
        } else bk[k] = -1;
    }
    __syncthreads();
    for (int i = t; i < NBKT; i += P1_THREADS) base[i] = atomicAdd(&bhead[i], cnt[i]);
    __syncthreads();
    #pragma unroll
    for (int k = 0; k < P1_PER_T; ++k)
        if (bk[k] >= 0)
            tmp[base[bk[k]] + rk[k]] = make_int2(pk[k], __float_as_int(vv[k]));
}

// One block per bucket: per-node count, scan, exact scatter — all in LDS.
__global__ __launch_bounds__(1024) void k_bucket(const int* __restrict__ bbase,
                                                 const int2* __restrict__ tmp,
                                                 int2* __restrict__ edges,
                                                 int* __restrict__ rp) {
    __shared__ int cnt[BKTSZ];
    __shared__ int sh[BKTSZ];
    const int b = blockIdx.x, t = threadIdx.x;
    const int start = bbase[b], end = bbase[b + 1];
    cnt[t] = 0;
    __syncthreads();
    for (int i = start + t; i < end; i += 1024) {
        const int x = tmp[i].x;
        atomicAdd(&cnt[(x >> 18) & (BKTSZ - 1)], 1);
    }
    __syncthreads();
    const int c = cnt[t];
    sh[t] = c; __syncthreads();
    for (int o = 1; o < BKTSZ; o <<= 1) {
        int a = (t >= o) ? sh[t - o] : 0;
        __syncthreads();
        sh[t] += a;
        __syncthreads();
    }
    const int ex = sh[t] - c;
    const int node = (b << BKT_SHIFT) + t;
    if (node < N_NODES) rp[node] = start + ex;
    cnt[t] = ex;
    __syncthreads();
    for (int i = start + t; i < end; i += 1024) {
        const int2 e = tmp[i];
        const int dloc = (e.x >> 18) & (BKTSZ - 1);
        const int pos = atomicAdd(&cnt[dloc], 1);
        edges[start + pos] = make_int2(e.x & SRC_MASK, e.y);
    }
}

// Pull SpMM, fp16 gather table (128B rows), f32 accumulate.
// 4 dst nodes per wave, 16 lanes x uint2 (4 halfs) per row.
// MODE 0: x = fp16 user_emb, skip item srcs; y16 <- acc; itemsum <- ie + acc.
// MODE 1: full gather; y16 <- acc; itemsum += acc.
// MODE 2: item dst rows only; no y; itemsum += acc.
template<int MODE>
__global__ __launch_bounds__(256) void k_spmm(const int* __restrict__ rp,
                                              const int2* __restrict__ edges,
                                              const uint2* __restrict__ x16,
                                              const float4* __restrict__ ie4,
                                              uint2* __restrict__ y16,
                                              float4* __restrict__ isum4) {
    const int wave = (blockIdx.x << 2) + (threadIdx.x >> 6);
    const int lane = threadIdx.x & 63;
    const int g = lane >> 4, q = lane & 15;
    int node = (wave << 2) + g;
    if (MODE == 2) node += N_USERS;

    int beg = 0, deg = 0;
    if (node < N_NODES) { beg = rp[node]; deg = rp[node + 1] - beg; }
    int m = max(deg, __shfl_xor(deg, 16));
    m = max(m, __shfl_xor(m, 32));
    const int nblk = (m + 15) >> 4;

    float4 acc = make_float4(0.f, 0.f, 0.f, 0.f);
    for (int bb = 0; bb < nblk; ++bb) {
        const int e = (bb << 4) + q;
        int2 ev = make_int2(0, 0);
        if (e < deg) ev = edges[beg + e];
        #pragma unroll
        for (int j = 0; j < 16; ++j) {
            const int   sj = __shfl(ev.x, (lane & 48) + j);
            const float vj = __int_as_float(__shfl(ev.y, (lane & 48) + j));
            bool act = true;
            if (MODE == 0) act = (sj < N_USERS);
            if (act) {
                const uint2 rw = x16[(size_t)sj * 16 + q];
                union { unsigned u; __half2 h; } c0, c1;
                c0.u = rw.x; c1.u = rw.y;
                const float2 f0 = __half22float2(c0.h);
                const float2 f1 = __half22float2(c1.h);
                acc.x = fmaf(vj, f0.x, acc.x);
                acc.y = fmaf(vj, f0.y, acc.y);
                acc.z = fmaf(vj, f1.x, acc.z);
                acc.w = fmaf(vj, f1.y, acc.w);
            }
        }
    }
    if (node < N_NODES) {
        if (MODE != 2) {
            union { unsigned u; __half2 h; } a0, a1;
            a0.h = __floats2half2_rn(acc.x, acc.y);
            a1.h = __floats2half2_rn(acc.z, acc.w);
            y16[(size_t)node * 16 + q] = make_uint2(a0.u, a1.u);
        }
        if (node >= N_USERS) {
            const size_t io = (size_t)(node - N_USERS) * 16 + q;
            if (MODE == 0) {
                const float4 iv = ie4[io];
                isum4[io] = make_float4(iv.x + acc.x, iv.y + acc.y, iv.z + acc.z, iv.w + acc.w);
            } else {
                float4 tv = isum4[io];
                tv.x += acc.x; tv.y += acc.y; tv.z += acc.z; tv.w += acc.w;
                isum4[io] = tv;
            }
        }
    }
}

// one wave per batch element: gamma = u.b + (u^T W) . (itemsum*0.25)
__global__ __launch_bounds__(256) void k_final(const float* __restrict__ ue,
                                               const float* __restrict__ isum,
                                               const float* __restrict__ W,
                                               const float* __restrict__ bvec,
                                               const int* __restrict__ users,
                                               const int* __restrict__ items,
                                               float* __restrict__ out) {
    __shared__ float Ws[DIM * DIM];
    const int t = threadIdx.x;
    for (int i = t; i < DIM * DIM; i += 256) Ws[i] = W[i];
    __syncthreads();

    const int gw = blockIdx.x * 4 + (t >> 6);
    const int lane = t & 63;
    if (gw >= BATCH) return;
    const int u  = users[gw];
    const int it = items[gw];

    float u_l = ue[(size_t)u * DIM + lane];
    float m_l = isum[(size_t)it * DIM + lane] * 0.25f;
    float b_l = bvec[lane];

    float v = 0.0f;
    for (int j = 0; j < DIM; ++j) {
        float uj = __shfl(u_l, j);
        v = fmaf(uj, Ws[j * DIM + lane], v);
    }
    float p = fmaf(v, m_l, u_l * b_l);
    for (int o = 32; o > 0; o >>= 1) p += __shfl_xor(p, o);
    if (lane == 0) out[gw] = p;
}

extern "C" void kernel_launch(void* const* d_in, const int* in_sizes, int n_in,
                              void* d_out, int out_size, void* d_ws, size_t ws_size,
                              hipStream_t stream) {
    const float* user_emb  = (const float*)d_in[0];
    const float* item_emb0 = (const float*)d_in[1];
    const float* edge_val  = (const float*)d_in[2];
    const float* W         = (const float*)d_in[3];
    const float* bvec      = (const float*)d_in[4];
    const int*   edge_src  = (const int*)d_in[5];
    const int*   edge_dst  = (const int*)d_in[6];
    const int*   users     = (const int*)d_in[7];
    const int*   items     = (const int*)d_in[8];
    float* out = (float*)d_out;

    char* ws = (char*)d_ws;
    uint2* bufA16  = (uint2*)(ws + 0);
    uint2* bufB16  = (uint2*)(ws + 19200000);
    uint2* xu16    = (uint2*)(ws + 38400000);
    float* itemsum = (float*)(ws + 51200000);
    int2*  edges   = (int2*) (ws + 64000000);
    int2*  tmp     = (int2*) (ws + 89600000);
    int*   rp      = (int*)  (ws + 115200000);
    int*   ghist   = (int*)  (ws + 115800064);
    int*   bbase   = (int*)  (ws + 115801088);
    int*   bhead   = (int*)  (ws + 115802112);

    // CSR build (all fine-grained atomics in LDS)
    k_zero_i32<<<1, 256, 0, stream>>>(ghist, NBKT);
    k_hist147<<<512, 256, 0, stream>>>(edge_dst, ghist);
    k_scan147<<<1, 256, 0, stream>>>(ghist, bbase, bhead, rp);
    k_pass1<<<P1_BLOCKS, P1_THREADS, 0, stream>>>(edge_src, edge_dst, edge_val, bhead, tmp);
    k_bucket<<<NBKT, 1024, 0, stream>>>(bbase, tmp, edges, rp);

    // fp16 user table for layer 1
    k_conv<<<2048, 256, 0, stream>>>((const float4*)user_emb, xu16);

    // 3 SpMM layers (fp16 gather, f32 accumulate)
    const int blocks_all   = (N_NODES + 15) / 16;   // 9375
    const int blocks_items = (N_ITEMS + 15) / 16;   // 3125
    k_spmm<0><<<blocks_all, 256, 0, stream>>>(rp, edges, xu16,
                                              (const float4*)item_emb0,
                                              bufB16, (float4*)itemsum);
    k_spmm<1><<<blocks_all, 256, 0, stream>>>(rp, edges, bufB16,
                                              nullptr, bufA16, (float4*)itemsum);
    k_spmm<2><<<blocks_items, 256, 0, stream>>>(rp, edges, bufA16,
                                                nullptr, nullptr, (float4*)itemsum);

    // final dot products
    k_final<<<(BATCH + 3) / 4, 256, 0, stream>>>(user_emb, itemsum, W, bvec,
                                                 users, items, out);
}

// Round 7
// 253.676 us; speedup vs baseline: 15.8069x; 1.0859x over previous
//
#include <hip/hip_runtime.h>
#include <hip/hip_fp16.h>

#define N_USERS 100000
#define N_ITEMS 50000
#define N_NODES 150000
#define NNZ     3200000
#define DIM     64
#define BATCH   8192

#define BKT_SHIFT 10
#define BKTSZ     (1 << BKT_SHIFT)                        // 1024 nodes / bucket
#define NBKT      ((N_NODES + BKTSZ - 1) >> BKT_SHIFT)    // 147
#define SRC_MASK  0x3FFFF                                 // 18 bits (N_NODES < 2^18)

#define P1_THREADS 512
#define P1_PER_T   16
#define P1_CHUNK   (P1_THREADS * P1_PER_T)                // 8192 edges / block
#define P1_BLOCKS  ((NNZ + P1_CHUNK - 1) / P1_CHUNK)      // 391

// ---------------- workspace layout (bytes) ----------------
// 0           bufA16   19,200,000   (150000*64*2, fp16)
// 19200000    bufB16   19,200,000
// 38400000    xu16     12,800,000   (100000*64*2, fp16 user_emb)
// 51200000    itemsum  12,800,000   (f32)
// 64000000    edges    25,600,064   (NNZ * int2 + 8-entry zero pad)
// 89600128    tmp      25,600,000   (NNZ * int2, binning scratch)
// 115200128   rp          600,064   (N_NODES+1)
// 115800192   ghist         1,024
// 115801216   bbase         1,024
// 115802240   bhead         1,024
// total ≈ 115.8 MB

__global__ __launch_bounds__(256) void k_zero_i32(int* __restrict__ p, int n) {
    for (int i = blockIdx.x * blockDim.x + threadIdx.x; i < n; i += gridDim.x * blockDim.x)
        p[i] = 0;
}

// f32 user_emb -> fp16 gather table
__global__ __launch_bounds__(256) void k_conv(const float4* __restrict__ ue,
                                              uint2* __restrict__ xu) {
    const int n = N_USERS * 16;
    for (int i = blockIdx.x * blockDim.x + threadIdx.x; i < n; i += gridDim.x * blockDim.x) {
        float4 v = ue[i];
        union { unsigned u; __half2 h; } a0, a1;
        a0.h = __floats2half2_rn(v.x, v.y);
        a1.h = __floats2half2_rn(v.z, v.w);
        xu[i] = make_uint2(a0.u, a1.u);
    }
}

// coarse 147-bucket histogram, LDS-privatized
__global__ __launch_bounds__(256) void k_hist147(const int* __restrict__ dst, int* __restrict__ gh) {
    __shared__ int h[NBKT];
    for (int i = threadIdx.x; i < NBKT; i += 256) h[i] = 0;
    __syncthreads();
    for (int i = blockIdx.x * 256 + threadIdx.x; i < NNZ; i += gridDim.x * 256)
        atomicAdd(&h[dst[i] >> BKT_SHIFT], 1);
    __syncthreads();
    for (int i = threadIdx.x; i < NBKT; i += 256) atomicAdd(&gh[i], h[i]);
}

// exclusive scan of 147 bucket counts
__global__ __launch_bounds__(256) void k_scan147(const int* __restrict__ gh,
                                                 int* __restrict__ bbase,
                                                 int* __restrict__ bhead,
                                                 int* __restrict__ rp) {
    __shared__ int sh[256];
    const int t = threadIdx.x;
    int v = (t < NBKT) ? gh[t] : 0;
    sh[t] = v; __syncthreads();
    for (int o = 1; o < 256; o <<= 1) {
        int a = (t >= o) ? sh[t - o] : 0;
        __syncthreads();
        sh[t] += a;
        __syncthreads();
    }
    int ex = sh[t] - v;
    if (t < NBKT) { bbase[t] = ex; bhead[t] = ex; }
    if (t == 0)   { bbase[NBKT] = NNZ; rp[N_NODES] = NNZ; }
}

// Pass 1: bin edges into 147 buckets; block-local LDS ranking -> contiguous runs.
__global__ __launch_bounds__(P1_THREADS) void k_pass1(const int* __restrict__ src,
                                                      const int* __restrict__ dst,
                                                      const float* __restrict__ val,
                                                      int* __restrict__ bhead,
                                                      int2* __restrict__ tmp) {
    __shared__ int cnt[NBKT];
    __shared__ int base[NBKT];
    const int t = threadIdx.x;
    const int c0 = blockIdx.x * P1_CHUNK;
    for (int i = t; i < NBKT; i += P1_THREADS) cnt[i] = 0;
    __syncthreads();
    int pk[P1_PER_T], rk[P1_PER_T], bk[P1_PER_T]; float vv[P1_PER_T];
    #pragma unroll
    for (int k = 0; k < P1_PER_T; ++k) {
        const int i = c0 + k * P1_THREADS + t;
        if (i < NNZ) {
            const int d = dst[i];
            bk[k] = d >> BKT_SHIFT;
            pk[k] = src[i] | ((d & (BKTSZ - 1)) << 18);
            vv[k] = val[i];
            rk[k] = atomicAdd(&cnt[bk[k]], 1);
        } else bk[k] = -1;
    }
    __syncthreads();
    for (int i = t; i < NBKT; i += P1_THREADS) base[i] = atomicAdd(&bhead[i], cnt[i]);
    __syncthreads();
    #pragma unroll
    for (int k = 0; k < P1_PER_T; ++k)
        if (bk[k] >= 0)
            tmp[base[bk[k]] + rk[k]] = make_int2(pk[k], __float_as_int(vv[k]));
}

// One block per bucket: per-node count, scan, exact scatter — all in LDS.
__global__ __launch_bounds__(1024) void k_bucket(const int* __restrict__ bbase,
                                                 const int2* __restrict__ tmp,
                                                 int2* __restrict__ edges,
                                                 int* __restrict__ rp) {
    __shared__ int cnt[BKTSZ];
    __shared__ int sh[BKTSZ];
    const int b = blockIdx.x, t = threadIdx.x;
    const int start = bbase[b], end = bbase[b + 1];
    cnt[t] = 0;
    __syncthreads();
    for (int i = start + t; i < end; i += 1024) {
        const int x = tmp[i].x;
        atomicAdd(&cnt[(x >> 18) & (BKTSZ - 1)], 1);
    }
    __syncthreads();
    const int c = cnt[t];
    sh[t] = c; __syncthreads();
    for (int o = 1; o < BKTSZ; o <<= 1) {
        int a = (t >= o) ? sh[t - o] : 0;
        __syncthreads();
        sh[t] += a;
        __syncthreads();
    }
    const int ex = sh[t] - c;
    const int node = (b << BKT_SHIFT) + t;
    if (node < N_NODES) rp[node] = start + ex;
    cnt[t] = ex;
    __syncthreads();
    for (int i = start + t; i < end; i += 1024) {
        const int2 e = tmp[i];
        const int dloc = (e.x >> 18) & (BKTSZ - 1);
        const int pos = atomicAdd(&cnt[dloc], 1);
        edges[start + pos] = make_int2(e.x & SRC_MASK, e.y);
    }
}

// Pull SpMM, fp16 gather (128B rows), f32 accumulate, 8-deep gather pipeline.
// One node per 16-lane group (no cross-group coupling, no shuffles).
// Masked edges (item src in MODE 0, past-segment slots) get BOTH val=0 AND
// index clamped to 0 — the unconditional gather stays on real in-bounds data,
// so 0*finite=0. (Round-6 bug: unclamped item srcs read past the 100000-row
// xu16 table -> fp16-reinterpreted garbage -> 0*NaN=NaN.)
// MODE 0: x = fp16 user_emb (100000 rows), item srcs masked;
//         y16 <- acc; itemsum <- ie + acc.
// MODE 1: full gather; y16 <- acc; itemsum += acc.
// MODE 2: item dst rows only; no y; itemsum += acc.
template<int MODE>
__global__ __launch_bounds__(256) void k_spmm(const int* __restrict__ rp,
                                              const int2* __restrict__ edges,
                                              const uint2* __restrict__ x16,
                                              const float4* __restrict__ ie4,
                                              uint2* __restrict__ y16,
                                              float4* __restrict__ isum4) {
    const int wave = (blockIdx.x << 2) + (threadIdx.x >> 6);
    const int lane = threadIdx.x & 63;
    const int g = lane >> 4, q = lane & 15;
    int node = (wave << 2) + g;
    if (MODE == 2) node += N_USERS;
    // grids divide exactly: no node >= N_NODES tail

    const int beg = rp[node];
    const int deg = rp[node + 1] - beg;

    float4 acc = make_float4(0.f, 0.f, 0.f, 0.f);
    for (int bb = 0; bb < deg; bb += 8) {
        int   se[8]; float ve[8];
        // phase 1: edge descriptors (sequential, L1-hot; 8-entry zero pad
        // keeps beg+bb+7 in bounds for the last node)
        #pragma unroll
        for (int k = 0; k < 8; ++k) {
            const int2 ed = edges[beg + bb + k];
            int   s = ed.x;
            float v = __int_as_float(ed.y);
            if (MODE == 0 && s >= N_USERS) { s = 0; v = 0.f; }  // item src: zero row
            if ((bb + k) >= deg)           { s = 0; v = 0.f; }  // past segment
            se[k] = s;
            ve[k] = v;
        }
        // phase 2: 8 independent row-gathers in flight
        uint2 rw[8];
        #pragma unroll
        for (int k = 0; k < 8; ++k)
            rw[k] = x16[(size_t)se[k] * 16 + q];
        // phase 3: convert + FMA
        #pragma unroll
        for (int k = 0; k < 8; ++k) {
            union { unsigned u; __half2 h; } c0, c1;
            c0.u = rw[k].x; c1.u = rw[k].y;
            const float2 f0 = __half22float2(c0.h);
            const float2 f1 = __half22float2(c1.h);
            acc.x = fmaf(ve[k], f0.x, acc.x);
            acc.y = fmaf(ve[k], f0.y, acc.y);
            acc.z = fmaf(ve[k], f1.x, acc.z);
            acc.w = fmaf(ve[k], f1.y, acc.w);
        }
    }

    if (MODE != 2) {
        union { unsigned u; __half2 h; } a0, a1;
        a0.h = __floats2half2_rn(acc.x, acc.y);
        a1.h = __floats2half2_rn(acc.z, acc.w);
        y16[(size_t)node * 16 + q] = make_uint2(a0.u, a1.u);
    }
    if (node >= N_USERS) {
        const size_t io = (size_t)(node - N_USERS) * 16 + q;
        if (MODE == 0) {
            const float4 iv = ie4[io];
            isum4[io] = make_float4(iv.x + acc.x, iv.y + acc.y, iv.z + acc.z, iv.w + acc.w);
        } else {
            float4 tv = isum4[io];
            tv.x += acc.x; tv.y += acc.y; tv.z += acc.z; tv.w += acc.w;
            isum4[io] = tv;
        }
    }
}

// one wave per batch element: gamma = u.b + (u^T W) . (itemsum*0.25)
__global__ __launch_bounds__(256) void k_final(const float* __restrict__ ue,
                                               const float* __restrict__ isum,
                                               const float* __restrict__ W,
                                               const float* __restrict__ bvec,
                                               const int* __restrict__ users,
                                               const int* __restrict__ items,
                                               float* __restrict__ out) {
    __shared__ float Ws[DIM * DIM];
    const int t = threadIdx.x;
    for (int i = t; i < DIM * DIM; i += 256) Ws[i] = W[i];
    __syncthreads();

    const int gw = blockIdx.x * 4 + (t >> 6);
    const int lane = t & 63;
    if (gw >= BATCH) return;
    const int u  = users[gw];
    const int it = items[gw];

    float u_l = ue[(size_t)u * DIM + lane];
    float m_l = isum[(size_t)it * DIM + lane] * 0.25f;
    float b_l = bvec[lane];

    float v = 0.0f;
    for (int j = 0; j < DIM; ++j) {
        float uj = __shfl(u_l, j);
        v = fmaf(uj, Ws[j * DIM + lane], v);
    }
    float p = fmaf(v, m_l, u_l * b_l);
    for (int o = 32; o > 0; o >>= 1) p += __shfl_xor(p, o);
    if (lane == 0) out[gw] = p;
}

extern "C" void kernel_launch(void* const* d_in, const int* in_sizes, int n_in,
                              void* d_out, int out_size, void* d_ws, size_t ws_size,
                              hipStream_t stream) {
    const float* user_emb  = (const float*)d_in[0];
    const float* item_emb0 = (const float*)d_in[1];
    const float* edge_val  = (const float*)d_in[2];
    const float* W         = (const float*)d_in[3];
    const float* bvec      = (const float*)d_in[4];
    const int*   edge_src  = (const int*)d_in[5];
    const int*   edge_dst  = (const int*)d_in[6];
    const int*   users     = (const int*)d_in[7];
    const int*   items     = (const int*)d_in[8];
    float* out = (float*)d_out;

    char* ws = (char*)d_ws;
    uint2* bufA16  = (uint2*)(ws + 0);
    uint2* bufB16  = (uint2*)(ws + 19200000);
    uint2* xu16    = (uint2*)(ws + 38400000);
    float* itemsum = (float*)(ws + 51200000);
    int2*  edges   = (int2*) (ws + 64000000);       // NNZ + 8 pad entries
    int2*  tmp     = (int2*) (ws + 89600128);
    int*   rp      = (int*)  (ws + 115200128);
    int*   ghist   = (int*)  (ws + 115800192);
    int*   bbase   = (int*)  (ws + 115801216);
    int*   bhead   = (int*)  (ws + 115802240);

    // CSR build (all fine-grained atomics in LDS)
    k_zero_i32<<<1, 256, 0, stream>>>(ghist, NBKT);
    k_zero_i32<<<1, 64, 0, stream>>>((int*)(edges + NNZ), 16);   // zero pad
    k_hist147<<<512, 256, 0, stream>>>(edge_dst, ghist);
    k_scan147<<<1, 256, 0, stream>>>(ghist, bbase, bhead, rp);
    k_pass1<<<P1_BLOCKS, P1_THREADS, 0, stream>>>(edge_src, edge_dst, edge_val, bhead, tmp);
    k_bucket<<<NBKT, 1024, 0, stream>>>(bbase, tmp, edges, rp);

    // fp16 user table for layer 1
    k_conv<<<2048, 256, 0, stream>>>((const float4*)user_emb, xu16);

    // 3 SpMM layers (fp16 gather, f32 accumulate)
    const int blocks_all   = N_NODES / 16;   // 9375 (exact)
    const int blocks_items = N_ITEMS / 16;   // 3125 (exact)
    k_spmm<0><<<blocks_all, 256, 0, stream>>>(rp, edges, xu16,
                                              (const float4*)item_emb0,
                                              bufB16, (float4*)itemsum);
    k_spmm<1><<<blocks_all, 256, 0, stream>>>(rp, edges, bufB16,
                                              nullptr, bufA16, (float4*)itemsum);
    k_spmm<2><<<blocks_items, 256, 0, stream>>>(rp, edges, bufA16,
                                                nullptr, nullptr, (float4*)itemsum);

    // final dot products
    k_final<<<(BATCH + 3) / 4, 256, 0, stream>>>(user_emb, itemsum, W, bvec,
                                                 users, items, out);
}

// Round 8
// 245.849 us; speedup vs baseline: 16.3101x; 1.0318x over previous
//
#include <hip/hip_runtime.h>
#include <hip/hip_fp16.h>

#define N_USERS 100000
#define N_ITEMS 50000
#define N_NODES 150000
#define NNZ     3200000
#define DIM     64
#define BATCH   8192

#define BKT_SHIFT 10
#define BKTSZ     (1 << BKT_SHIFT)                        // 1024 nodes / bucket
#define NBKT      ((N_NODES + BKTSZ - 1) >> BKT_SHIFT)    // 147
#define SRC_MASK  0x3FFFF                                 // 18 bits (N_NODES < 2^18)

#define P1_THREADS 512
#define P1_PER_T   16
#define P1_CHUNK   (P1_THREADS * P1_PER_T)                // 8192 edges / block
#define P1_BLOCKS  ((NNZ + P1_CHUNK - 1) / P1_CHUNK)      // 391

// ---------------- workspace layout (bytes) ----------------
// 0           bufA16   19,200,000   (150000*64*2, fp16)
// 19200000    bufB16   19,200,000
// 38400000    xu16     12,800,000   (100000*64*2, fp16 user_emb)
// 51200000    itemsum  12,800,000   (f32)
// 64000000    edges    25,600,128   (NNZ * int2 + 16-entry zero pad)
// 89600128    tmp      25,600,000   (NNZ * int2, binning scratch)
// 115200128   rp          600,064   (N_NODES+1)
// 115800192   ucnt        600,064   (per-node user-src edge count)
// 116400256   ghist         1,024
// 116401280   bbase         1,024
// 116402304   bhead         1,024
// total ≈ 116.4 MB

// zero ghist + edge pad in one tiny launch
__global__ __launch_bounds__(256) void k_prep(int* __restrict__ ghist, int* __restrict__ pad) {
    const int t = threadIdx.x;
    if (t < NBKT) ghist[t] = 0;
    if (t >= 224) pad[t - 224] = 0;   // 32 ints = 16 int2 pad entries
}

// f32 user_emb -> fp16 gather table
__global__ __launch_bounds__(256) void k_conv(const float4* __restrict__ ue,
                                              uint2* __restrict__ xu) {
    const int n = N_USERS * 16;
    for (int i = blockIdx.x * blockDim.x + threadIdx.x; i < n; i += gridDim.x * blockDim.x) {
        float4 v = ue[i];
        union { unsigned u; __half2 h; } a0, a1;
        a0.h = __floats2half2_rn(v.x, v.y);
        a1.h = __floats2half2_rn(v.z, v.w);
        xu[i] = make_uint2(a0.u, a1.u);
    }
}

// coarse 147-bucket histogram, LDS-privatized
__global__ __launch_bounds__(256) void k_hist147(const int* __restrict__ dst, int* __restrict__ gh) {
    __shared__ int h[NBKT];
    for (int i = threadIdx.x; i < NBKT; i += 256) h[i] = 0;
    __syncthreads();
    for (int i = blockIdx.x * 256 + threadIdx.x; i < NNZ; i += gridDim.x * 256)
        atomicAdd(&h[dst[i] >> BKT_SHIFT], 1);
    __syncthreads();
    for (int i = threadIdx.x; i < NBKT; i += 256) atomicAdd(&gh[i], h[i]);
}

// exclusive scan of 147 bucket counts
__global__ __launch_bounds__(256) void k_scan147(const int* __restrict__ gh,
                                                 int* __restrict__ bbase,
                                                 int* __restrict__ bhead,
                                                 int* __restrict__ rp) {
    __shared__ int sh[256];
    const int t = threadIdx.x;
    int v = (t < NBKT) ? gh[t] : 0;
    sh[t] = v; __syncthreads();
    for (int o = 1; o < 256; o <<= 1) {
        int a = (t >= o) ? sh[t - o] : 0;
        __syncthreads();
        sh[t] += a;
        __syncthreads();
    }
    int ex = sh[t] - v;
    if (t < NBKT) { bbase[t] = ex; bhead[t] = ex; }
    if (t == 0)   { bbase[NBKT] = NNZ; rp[N_NODES] = NNZ; }
}

// Pass 1: bin edges into 147 buckets; block-local LDS ranking -> contiguous runs.
__global__ __launch_bounds__(P1_THREADS) void k_pass1(const int* __restrict__ src,
                                                      const int* __restrict__ dst,
                                                      const float* __restrict__ val,
                                                      int* __restrict__ bhead,
                                                      int2* __restrict__ tmp) {
    __shared__ int cnt[NBKT];
    __shared__ int base[NBKT];
    const int t = threadIdx.x;
    const int c0 = blockIdx.x * P1_CHUNK;
    for (int i = t; i < NBKT; i += P1_THREADS) cnt[i] = 0;
    __syncthreads();
    int pk[P1_PER_T], rk[P1_PER_T], bk[P1_PER_T]; float vv[P1_PER_T];
    #pragma unroll
    for (int k = 0; k < P1_PER_T; ++k) {
        const int i = c0 + k * P1_THREADS + t;
        if (i < NNZ) {
            const int d = dst[i];
            bk[k] = d >> BKT_SHIFT;
            pk[k] = src[i] | ((d & (BKTSZ - 1)) << 18);
            vv[k] = val[i];
            rk[k] = atomicAdd(&cnt[bk[k]], 1);
        } else bk[k] = -1;
    }
    __syncthreads();
    for (int i = t; i < NBKT; i += P1_THREADS) base[i] = atomicAdd(&bhead[i], cnt[i]);
    __syncthreads();
    #pragma unroll
    for (int k = 0; k < P1_PER_T; ++k)
        if (bk[k] >= 0)
            tmp[base[bk[k]] + rk[k]] = make_int2(pk[k], __float_as_int(vv[k]));
}

// One block per bucket: per-(node,class) count, pair-scan, exact scatter.
// Each node's segment is partitioned [user-src edges | item-src edges];
// ucnt[node] = user-src count so layer 1 can iterate only the prefix.
__global__ __launch_bounds__(1024) void k_bucket(const int* __restrict__ bbase,
                                                 const int2* __restrict__ tmp,
                                                 int2* __restrict__ edges,
                                                 int* __restrict__ rp,
                                                 int* __restrict__ ucnt) {
    __shared__ int cnt[BKTSZ * 2];
    __shared__ int sh[BKTSZ];
    const int b = blockIdx.x, t = threadIdx.x;
    const int start = bbase[b], end = bbase[b + 1];
    cnt[t] = 0; cnt[t + BKTSZ] = 0;
    __syncthreads();
    for (int i = start + t; i < end; i += 1024) {
        const int x = tmp[i].x;
        const int dloc = (x >> 18) & (BKTSZ - 1);
        const int cls = ((x & SRC_MASK) >= N_USERS) ? 1 : 0;
        atomicAdd(&cnt[dloc * 2 + cls], 1);
    }
    __syncthreads();
    const int c0 = cnt[2 * t], c1 = cnt[2 * t + 1];
    const int s = c0 + c1;
    sh[t] = s; __syncthreads();
    for (int o = 1; o < BKTSZ; o <<= 1) {
        int a = (t >= o) ? sh[t - o] : 0;
        __syncthreads();
        sh[t] += a;
        __syncthreads();
    }
    const int ex = sh[t] - s;
    const int node = (b << BKT_SHIFT) + t;
    if (node < N_NODES) { rp[node] = start + ex; ucnt[node] = c0; }
    cnt[2 * t] = ex;            // running head, user class (bucket-relative)
    cnt[2 * t + 1] = ex + c0;   // running head, item class
    __syncthreads();
    for (int i = start + t; i < end; i += 1024) {
        const int2 e = tmp[i];
        const int src  = e.x & SRC_MASK;
        const int dloc = (e.x >> 18) & (BKTSZ - 1);
        const int cls  = (src >= N_USERS) ? 1 : 0;
        const int pos = atomicAdd(&cnt[dloc * 2 + cls], 1);
        edges[start + pos] = make_int2(src, e.y);
    }
}

// Pull SpMM, fp16 gather (128B rows), f32 accumulate, 8-deep gather pipeline.
// One node per 16-lane group (no cross-group coupling, no shuffles).
// Past-segment slots clamp index to 0 and val to 0 (gather stays in-bounds,
// 0*finite=0).
// MODE 0: x = fp16 user_emb (100000 rows); iterates ONLY the user-src prefix
//         (deg = ucnt[node]); y16 <- acc; itemsum <- ie + acc.
// MODE 1: full segment; y16 <- acc; itemsum += acc.
// MODE 2: item dst rows only; full segment; no y; itemsum += acc.
template<int MODE>
__global__ __launch_bounds__(256) void k_spmm(const int* __restrict__ rp,
                                              const int* __restrict__ ucnt,
                                              const int2* __restrict__ edges,
                                              const uint2* __restrict__ x16,
                                              const float4* __restrict__ ie4,
                                              uint2* __restrict__ y16,
                                              float4* __restrict__ isum4) {
    const int wave = (blockIdx.x << 2) + (threadIdx.x >> 6);
    const int lane = threadIdx.x & 63;
    const int g = lane >> 4, q = lane & 15;
    int node = (wave << 2) + g;
    if (MODE == 2) node += N_USERS;
    // grids divide exactly: no node >= N_NODES tail

    const int beg = rp[node];
    const int deg = (MODE == 0) ? ucnt[node] : (rp[node + 1] - beg);

    float4 acc = make_float4(0.f, 0.f, 0.f, 0.f);
    for (int bb = 0; bb < deg; bb += 8) {
        int   se[8]; float ve[8];
        // phase 1: edge descriptors (sequential, L1-hot; 16-entry zero pad
        // keeps beg+bb+7 in bounds for the global last segment)
        #pragma unroll
        for (int k = 0; k < 8; ++k) {
            const int2 ed = edges[beg + bb + k];
            const bool ok = (bb + k) < deg;
            se[k] = ok ? ed.x : 0;
            ve[k] = ok ? __int_as_float(ed.y) : 0.f;
        }
        // phase 2: 8 independent row-gathers in flight
        uint2 rw[8];
        #pragma unroll
        for (int k = 0; k < 8; ++k)
            rw[k] = x16[(size_t)se[k] * 16 + q];
        // phase 3: convert + FMA
        #pragma unroll
        for (int k = 0; k < 8; ++k) {
            union { unsigned u; __half2 h; } c0, c1;
            c0.u = rw[k].x; c1.u = rw[k].y;
            const float2 f0 = __half22float2(c0.h);
            const float2 f1 = __half22float2(c1.h);
            acc.x = fmaf(ve[k], f0.x, acc.x);
            acc.y = fmaf(ve[k], f0.y, acc.y);
            acc.z = fmaf(ve[k], f1.x, acc.z);
            acc.w = fmaf(ve[k], f1.y, acc.w);
        }
    }

    if (MODE != 2) {
        union { unsigned u; __half2 h; } a0, a1;
        a0.h = __floats2half2_rn(acc.x, acc.y);
        a1.h = __floats2half2_rn(acc.z, acc.w);
        y16[(size_t)node * 16 + q] = make_uint2(a0.u, a1.u);
    }
    if (node >= N_USERS) {
        const size_t io = (size_t)(node - N_USERS) * 16 + q;
        if (MODE == 0) {
            const float4 iv = ie4[io];
            isum4[io] = make_float4(iv.x + acc.x, iv.y + acc.y, iv.z + acc.z, iv.w + acc.w);
        } else {
            float4 tv = isum4[io];
            tv.x += acc.x; tv.y += acc.y; tv.z += acc.z; tv.w += acc.w;
            isum4[io] = tv;
        }
    }
}

// one wave per batch element: gamma = u.b + (u^T W) . (itemsum*0.25)
__global__ __launch_bounds__(256) void k_final(const float* __restrict__ ue,
                                               const float* __restrict__ isum,
                                               const float* __restrict__ W,
                                               const float* __restrict__ bvec,
                                               const int* __restrict__ users,
                                               const int* __restrict__ items,
                                               float* __restrict__ out) {
    __shared__ float Ws[DIM * DIM];
    const int t = threadIdx.x;
    for (int i = t; i < DIM * DIM; i += 256) Ws[i] = W[i];
    __syncthreads();

    const int gw = blockIdx.x * 4 + (t >> 6);
    const int lane = t & 63;
    if (gw >= BATCH) return;
    const int u  = users[gw];
    const int it = items[gw];

    float u_l = ue[(size_t)u * DIM + lane];
    float m_l = isum[(size_t)it * DIM + lane] * 0.25f;
    float b_l = bvec[lane];

    float v = 0.0f;
    for (int j = 0; j < DIM; ++j) {
        float uj = __shfl(u_l, j);
        v = fmaf(uj, Ws[j * DIM + lane], v);
    }
    float p = fmaf(v, m_l, u_l * b_l);
    for (int o = 32; o > 0; o >>= 1) p += __shfl_xor(p, o);
    if (lane == 0) out[gw] = p;
}

extern "C" void kernel_launch(void* const* d_in, const int* in_sizes, int n_in,
                              void* d_out, int out_size, void* d_ws, size_t ws_size,
                              hipStream_t stream) {
    const float* user_emb  = (const float*)d_in[0];
    const float* item_emb0 = (const float*)d_in[1];
    const float* edge_val  = (const float*)d_in[2];
    const float* W         = (const float*)d_in[3];
    const float* bvec      = (const float*)d_in[4];
    const int*   edge_src  = (const int*)d_in[5];
    const int*   edge_dst  = (const int*)d_in[6];
    const int*   users     = (const int*)d_in[7];
    const int*   items     = (const int*)d_in[8];
    float* out = (float*)d_out;

    char* ws = (char*)d_ws;
    uint2* bufA16  = (uint2*)(ws + 0);
    uint2* bufB16  = (uint2*)(ws + 19200000);
    uint2* xu16    = (uint2*)(ws + 38400000);
    float* itemsum = (float*)(ws + 51200000);
    int2*  edges   = (int2*) (ws + 64000000);       // NNZ + 16 pad entries
    int2*  tmp     = (int2*) (ws + 89600128);
    int*   rp      = (int*)  (ws + 115200128);
    int*   ucnt    = (int*)  (ws + 115800192);
    int*   ghist   = (int*)  (ws + 116400256);
    int*   bbase   = (int*)  (ws + 116401280);
    int*   bhead   = (int*)  (ws + 116402304);

    // CSR build (all fine-grained atomics in LDS)
    k_prep<<<1, 256, 0, stream>>>(ghist, (int*)(edges + NNZ));
    k_hist147<<<512, 256, 0, stream>>>(edge_dst, ghist);
    k_scan147<<<1, 256, 0, stream>>>(ghist, bbase, bhead, rp);
    k_pass1<<<P1_BLOCKS, P1_THREADS, 0, stream>>>(edge_src, edge_dst, edge_val, bhead, tmp);
    k_bucket<<<NBKT, 1024, 0, stream>>>(bbase, tmp, edges, rp, ucnt);

    // fp16 user table for layer 1
    k_conv<<<2048, 256, 0, stream>>>((const float4*)user_emb, xu16);

    // 3 SpMM layers (fp16 gather, f32 accumulate)
    const int blocks_all   = N_NODES / 16;   // 9375 (exact)
    const int blocks_items = N_ITEMS / 16;   // 3125 (exact)
    k_spmm<0><<<blocks_all, 256, 0, stream>>>(rp, ucnt, edges, xu16,
                                              (const float4*)item_emb0,
                                              bufB16, (float4*)itemsum);
    k_spmm<1><<<blocks_all, 256, 0, stream>>>(rp, ucnt, edges, bufB16,
                                              nullptr, bufA16, (float4*)itemsum);
    k_spmm<2><<<blocks_items, 256, 0, stream>>>(rp, ucnt, edges, bufA16,
                                                nullptr, nullptr, (float4*)itemsum);

    // final dot products
    k_final<<<(BATCH + 3) / 4, 256, 0, stream>>>(user_emb, itemsum, W, bvec,
                                                 users, items, out);
}